// Round 1
// baseline (327.344 us; speedup 1.0000x reference)
//
#include <hip/hip_runtime.h>

// OccGrid batched-dynamic query: nearest-keyframe + 3D occupancy gather.
// Problem constants (fixed by setup_inputs): R=96, F=16, B=4, N=2e6.

__global__ __launch_bounds__(256) void occ_query_kernel(
    const float* __restrict__ pts,       // (N,3)
    const float* __restrict__ ts,        // (N,)
    const float* __restrict__ occ,       // (B*F, R, R, R)
    const float* __restrict__ kf,        // (F,) sorted
    const int*   __restrict__ bidx,      // (N,)
    float*       __restrict__ out,       // (N,)
    int n)
{
    constexpr int R = 96;
    constexpr int F = 16;
    constexpr int R3 = R * R * R;

    // Keyframes are wave-uniform: compiler emits scalar loads; L1-resident.
    float k[F];
#pragma unroll
    for (int j = 0; j < F; ++j) k[j] = kf[j];

    const int stride = gridDim.x * blockDim.x;
    for (int i = blockIdx.x * blockDim.x + threadIdx.x; i < n; i += stride) {
        const float px = pts[3 * i + 0];
        const float py = pts[3 * i + 1];
        const float pz = pts[3 * i + 2];
        const float t  = ts[i];
        const int   b  = bidx[i];

        // gidx = clip(floor((p*0.5+0.5)*R), 0, R-1)
        int gx = (int)floorf((px * 0.5f + 0.5f) * (float)R);
        int gy = (int)floorf((py * 0.5f + 0.5f) * (float)R);
        int gz = (int)floorf((pz * 0.5f + 0.5f) * (float)R);
        gx = min(max(gx, 0), R - 1);
        gy = min(max(gy, 0), R - 1);
        gz = min(max(gz, 0), R - 1);

        // searchsorted(side='left'): ins = count of kf[j] < t
        int ins = 0;
#pragma unroll
        for (int j = 0; j < F; ++j) ins += (k[j] < t) ? 1 : 0;
        int lo = min(max(ins - 1, 0), F - 1);
        int hi = min(ins, F - 1);
        // hi wins only on strict <; ties -> lo (matches reference jnp.where)
        const int f = (fabsf(k[hi] - t) < fabsf(t - k[lo])) ? hi : lo;

        const int flat = (b * F + f) * R3 + (gx * R + gy) * R + gz;
        out[i] = occ[flat];
    }
}

extern "C" void kernel_launch(void* const* d_in, const int* in_sizes, int n_in,
                              void* d_out, int out_size, void* d_ws, size_t ws_size,
                              hipStream_t stream)
{
    const float* pts  = (const float*)d_in[0];
    const float* ts   = (const float*)d_in[1];
    const float* occ  = (const float*)d_in[2];
    const float* kf   = (const float*)d_in[3];
    const int*   bidx = (const int*)d_in[4];
    float* out = (float*)d_out;

    const int n = in_sizes[1];  // ts has N elements

    // Memory-bound: cap grid at ~8 blocks/CU and grid-stride the rest.
    int blocks = (n + 255) / 256;
    if (blocks > 2048) blocks = 2048;

    occ_query_kernel<<<blocks, 256, 0, stream>>>(pts, ts, occ, kf, bidx, out, n);
}

// Round 3
// 322.751 us; speedup vs baseline: 1.0142x; 1.0142x over previous
//
#include <hip/hip_runtime.h>

// OccGrid batched-dynamic query: nearest-keyframe + 3D occupancy gather.
// R=96, F=16, B=4, N=2e6. 4 queries/thread for 4x gather MLP; vectorized
// streaming I/O with non-temporal hints to keep occ_grid L2/L3-resident.
// NOTE: __builtin_nontemporal_* needs native clang vectors, not HIP float4.

typedef float f32x4 __attribute__((ext_vector_type(4)));
typedef int   i32x4 __attribute__((ext_vector_type(4)));

__global__ __launch_bounds__(256) void occ_query4_kernel(
    const float* __restrict__ pts,       // (N,3)
    const float* __restrict__ ts,        // (N,)
    const float* __restrict__ occ,       // (B*F, R, R, R)
    const float* __restrict__ kf,        // (F,) sorted
    const int*   __restrict__ bidx,      // (N,)
    float*       __restrict__ out,       // (N,)
    int n)
{
    constexpr int R  = 96;
    constexpr int F  = 16;
    constexpr int R3 = R * R * R;

    // Keyframes: wave-uniform scalar loads, L1-resident.
    float k[F];
#pragma unroll
    for (int j = 0; j < F; ++j) k[j] = kf[j];

    const int tid = blockIdx.x * blockDim.x + threadIdx.x;
    const int i0  = tid * 4;
    if (i0 >= n) return;

    if (i0 + 4 <= n) {
        // ---- fast path: 4 consecutive queries, fully vectorized ----
        const f32x4* p4 = (const f32x4*)pts;
        const f32x4 a  = __builtin_nontemporal_load(&p4[tid * 3 + 0]);
        const f32x4 b  = __builtin_nontemporal_load(&p4[tid * 3 + 1]);
        const f32x4 c  = __builtin_nontemporal_load(&p4[tid * 3 + 2]);
        const f32x4 t4 = __builtin_nontemporal_load(&((const f32x4*)ts)[tid]);
        const i32x4 b4 = __builtin_nontemporal_load(&((const i32x4*)bidx)[tid]);

        const float px[4] = {a.x, a.w, b.z, c.y};
        const float py[4] = {a.y, b.x, b.w, c.z};
        const float pz[4] = {a.z, b.y, c.x, c.w};
        const float tt[4] = {t4.x, t4.y, t4.z, t4.w};
        const int   bb[4] = {b4.x, b4.y, b4.z, b4.w};

        int flat[4];
#pragma unroll
        for (int q = 0; q < 4; ++q) {
            int gx = (int)floorf((px[q] * 0.5f + 0.5f) * (float)R);
            int gy = (int)floorf((py[q] * 0.5f + 0.5f) * (float)R);
            int gz = (int)floorf((pz[q] * 0.5f + 0.5f) * (float)R);
            gx = min(max(gx, 0), R - 1);
            gy = min(max(gy, 0), R - 1);
            gz = min(max(gz, 0), R - 1);

            int ins = 0;
#pragma unroll
            for (int j = 0; j < F; ++j) ins += (k[j] < tt[q]) ? 1 : 0;
            const int lo = min(max(ins - 1, 0), F - 1);
            const int hi = min(ins, F - 1);
            const int f  = (fabsf(k[hi] - tt[q]) < fabsf(tt[q] - k[lo])) ? hi : lo;

            flat[q] = (bb[q] * F + f) * R3 + (gx * R + gy) * R + gz;
        }

        // 4 independent gathers issued back-to-back (MLP=4).
        f32x4 r;
        r.x = occ[flat[0]];
        r.y = occ[flat[1]];
        r.z = occ[flat[2]];
        r.w = occ[flat[3]];
        __builtin_nontemporal_store(r, &((f32x4*)out)[tid]);
    } else {
        // ---- tail: scalar ----
        for (int i = i0; i < n; ++i) {
            const float px = pts[3 * i + 0];
            const float py = pts[3 * i + 1];
            const float pz = pts[3 * i + 2];
            const float t  = ts[i];
            const int   bq = bidx[i];

            int gx = (int)floorf((px * 0.5f + 0.5f) * (float)R);
            int gy = (int)floorf((py * 0.5f + 0.5f) * (float)R);
            int gz = (int)floorf((pz * 0.5f + 0.5f) * (float)R);
            gx = min(max(gx, 0), R - 1);
            gy = min(max(gy, 0), R - 1);
            gz = min(max(gz, 0), R - 1);

            int ins = 0;
#pragma unroll
            for (int j = 0; j < F; ++j) ins += (k[j] < t) ? 1 : 0;
            const int lo = min(max(ins - 1, 0), F - 1);
            const int hi = min(ins, F - 1);
            const int f  = (fabsf(k[hi] - t) < fabsf(t - k[lo])) ? hi : lo;

            out[i] = occ[(bq * F + f) * R3 + (gx * R + gy) * R + gz];
        }
    }
}

extern "C" void kernel_launch(void* const* d_in, const int* in_sizes, int n_in,
                              void* d_out, int out_size, void* d_ws, size_t ws_size,
                              hipStream_t stream)
{
    const float* pts  = (const float*)d_in[0];
    const float* ts   = (const float*)d_in[1];
    const float* occ  = (const float*)d_in[2];
    const float* kf   = (const float*)d_in[3];
    const int*   bidx = (const int*)d_in[4];
    float* out = (float*)d_out;

    const int n = in_sizes[1];          // ts has N elements
    const int nthreads = (n + 3) / 4;   // 4 queries per thread
    const int blocks = (nthreads + 255) / 256;

    occ_query4_kernel<<<blocks, 256, 0, stream>>>(pts, ts, occ, kf, bidx, out, n);
}